// Round 1
// baseline (867.715 us; speedup 1.0000x reference)
//
#include <hip/hip_runtime.h>
#include <math.h>

#define HID 128

// ---------------- CSR build ----------------
__global__ void zero_int_kernel(int* p, int n) {
    int i = blockIdx.x * blockDim.x + threadIdx.x;
    if (i < n) p[i] = 0;
}

__global__ void count_kernel(const int* __restrict__ dst, int* __restrict__ counts, int ne) {
    int i = blockIdx.x * blockDim.x + threadIdx.x;
    if (i < ne) atomicAdd(&counts[dst[i]], 1);
}

__global__ __launch_bounds__(1024) void scan_kernel(const int* __restrict__ counts,
                                                    int* __restrict__ offsets, int n) {
    __shared__ int part[1024];
    int t = threadIdx.x;
    int chunk = (n + 1023) >> 10;
    int base = t * chunk;
    int s = 0;
    for (int i = 0; i < chunk; i++) {
        int idx = base + i;
        if (idx < n) s += counts[idx];
    }
    part[t] = s;
    __syncthreads();
    // Hillis-Steele inclusive scan over 1024 partials
    for (int off = 1; off < 1024; off <<= 1) {
        int v = 0;
        if (t >= off) v = part[t - off];
        __syncthreads();
        if (t >= off) part[t] += v;
        __syncthreads();
    }
    int run = (t == 0) ? 0 : part[t - 1];
    for (int i = 0; i < chunk; i++) {
        int idx = base + i;
        if (idx < n) {
            offsets[idx] = run;
            run += counts[idx];
        }
    }
}

__global__ void copy_int_kernel(const int* __restrict__ a, int* __restrict__ b, int n) {
    int i = blockIdx.x * blockDim.x + threadIdx.x;
    if (i < n) b[i] = a[i];
}

__global__ void fill_kernel(const int* __restrict__ src, const int* __restrict__ dst,
                            int* __restrict__ cursor, int* __restrict__ esrc, int ne) {
    int i = blockIdx.x * blockDim.x + threadIdx.x;
    if (i < ne) {
        int d = dst[i];
        int pos = atomicAdd(&cursor[d], 1);
        esrc[pos] = src[i];
    }
}

// ---------------- dual GEMM: U = H@Wn, V = H@Wr ----------------
// block tile: 32 nodes x 128 cols, K-chunks of 16, 256 threads, 4x4 reg tile (x2 outputs)
__global__ __launch_bounds__(256) void gemm_dual_kernel(const float* __restrict__ H,
                                                        const float* __restrict__ Wn,
                                                        const float* __restrict__ Wr,
                                                        float* __restrict__ U,
                                                        float* __restrict__ V,
                                                        int N, int K) {
    __shared__ __align__(16) float As[16][32];    // [k][row]
    __shared__ __align__(16) float B1s[16][128];  // [k][col]
    __shared__ __align__(16) float B2s[16][128];
    int tid = threadIdx.x;
    int col_t = tid & 31;  // cols 4*col_t .. +3
    int row_t = tid >> 5;  // rows 4*row_t .. +3 (0..7)
    int n0 = blockIdx.x * 32;

    float accU[4][4], accV[4][4];
#pragma unroll
    for (int i = 0; i < 4; i++)
#pragma unroll
        for (int j = 0; j < 4; j++) { accU[i][j] = 0.f; accV[i][j] = 0.f; }

    int lk = tid & 15, lr = tid >> 4;   // A-tile loader coords
    int lc = tid & 127, lk0 = tid >> 7; // B-tile loader coords

    for (int kc = 0; kc < K; kc += 16) {
#pragma unroll
        for (int rr = lr; rr < 32; rr += 16) {
            int n = n0 + rr;
            int kk = kc + lk;
            float v = 0.f;
            if (n < N && kk < K) v = H[(size_t)n * K + kk];
            As[lk][rr] = v;
        }
#pragma unroll
        for (int k = lk0; k < 16; k += 2) {
            int kk = kc + k;
            float v1 = 0.f, v2 = 0.f;
            if (kk < K) {
                v1 = Wn[kk * HID + lc];
                v2 = Wr[kk * HID + lc];
            }
            B1s[k][lc] = v1;
            B2s[k][lc] = v2;
        }
        __syncthreads();
#pragma unroll
        for (int k = 0; k < 16; k++) {
            float4 a  = *(const float4*)&As[k][4 * row_t];
            float4 b1 = *(const float4*)&B1s[k][4 * col_t];
            float4 b2 = *(const float4*)&B2s[k][4 * col_t];
            float av[4]  = {a.x, a.y, a.z, a.w};
            float b1v[4] = {b1.x, b1.y, b1.z, b1.w};
            float b2v[4] = {b2.x, b2.y, b2.z, b2.w};
#pragma unroll
            for (int i = 0; i < 4; i++)
#pragma unroll
                for (int j = 0; j < 4; j++) {
                    accU[i][j] = fmaf(av[i], b1v[j], accU[i][j]);
                    accV[i][j] = fmaf(av[i], b2v[j], accV[i][j]);
                }
        }
        __syncthreads();
    }
#pragma unroll
    for (int i = 0; i < 4; i++) {
        int n = n0 + 4 * row_t + i;
        if (n < N) {
            float4 u = {accU[i][0], accU[i][1], accU[i][2], accU[i][3]};
            float4 v = {accV[i][0], accV[i][1], accV[i][2], accV[i][3]};
            *(float4*)&U[(size_t)n * HID + 4 * col_t] = u;
            *(float4*)&V[(size_t)n * HID + 4 * col_t] = v;
        }
    }
}

// ---------------- aggregation: Z[n] = mean_{e->n} U[src_e] + V[n] + b ----------------
__global__ __launch_bounds__(128) void agg_kernel(const float* __restrict__ U,
                                                  const float* __restrict__ V,
                                                  const float* __restrict__ bias,
                                                  const int* __restrict__ counts,
                                                  const int* __restrict__ offsets,
                                                  const int* __restrict__ esrc,
                                                  float* __restrict__ Z, int N) {
    int n = blockIdx.x;
    if (n >= N) return;
    int c = threadIdx.x;  // 0..127
    int deg = counts[n];
    int st = offsets[n];
    float a0 = 0.f, a1 = 0.f, a2 = 0.f, a3 = 0.f;
    int i = 0;
    for (; i + 3 < deg; i += 4) {
        int s0 = esrc[st + i];
        int s1 = esrc[st + i + 1];
        int s2 = esrc[st + i + 2];
        int s3 = esrc[st + i + 3];
        a0 += U[(size_t)s0 * HID + c];
        a1 += U[(size_t)s1 * HID + c];
        a2 += U[(size_t)s2 * HID + c];
        a3 += U[(size_t)s3 * HID + c];
    }
    for (; i < deg; i++) a0 += U[(size_t)esrc[st + i] * HID + c];
    float acc = (a0 + a1) + (a2 + a3);
    float d = (float)(deg > 1 ? deg : 1);
    Z[(size_t)n * HID + c] = acc / d + V[(size_t)n * HID + c] + bias[c];
}

// ---------------- BN stats (sum, sumsq per channel) ----------------
__global__ __launch_bounds__(128) void zero_stats_kernel(double* sums, double* sumsq) {
    int t = threadIdx.x;  // 128
    sums[t] = 0.0;
    sumsq[t] = 0.0;
}

__global__ __launch_bounds__(256) void stats_kernel(const float* __restrict__ Z,
                                                    double* __restrict__ sums,
                                                    double* __restrict__ sumsq, int N) {
    int c = threadIdx.x & 127;
    int half = threadIdx.x >> 7;
    int P = (N + gridDim.x - 1) / gridDim.x;
    int n0 = blockIdx.x * P;
    int n1 = n0 + P;
    if (n1 > N) n1 = N;
    float s = 0.f, q = 0.f;
    for (int n = n0 + half; n < n1; n += 2) {
        float z = Z[(size_t)n * HID + c];
        s += z;
        q += z * z;
    }
    __shared__ float bs[256], bq[256];
    bs[threadIdx.x] = s;
    bq[threadIdx.x] = q;
    __syncthreads();
    if (threadIdx.x < 128) {
        double S = (double)bs[threadIdx.x] + (double)bs[threadIdx.x + 128];
        double Q = (double)bq[threadIdx.x] + (double)bq[threadIdx.x + 128];
        atomicAdd(&sums[threadIdx.x], S);
        atomicAdd(&sumsq[threadIdx.x], Q);
    }
}

__global__ __launch_bounds__(128) void bn_finalize_kernel(const double* __restrict__ sums,
                                                          const double* __restrict__ sumsq,
                                                          const float* __restrict__ g,
                                                          const float* __restrict__ be,
                                                          float* __restrict__ scale,
                                                          float* __restrict__ shift, int N) {
    int c = threadIdx.x;  // 128
    double mu = sums[c] / (double)N;
    double var = sumsq[c] / (double)N - mu * mu;
    if (var < 0.0) var = 0.0;
    float rs = (float)(1.0 / sqrt(var + 1e-5));
    float sc = g[c] * rs;
    scale[c] = sc;
    shift[c] = be[c] - (float)mu * sc;
}

__global__ __launch_bounds__(256) void bn_relu_kernel(const float* __restrict__ Z,
                                                      const float* __restrict__ scale,
                                                      const float* __restrict__ shift,
                                                      float* __restrict__ H, int total4) {
    int i = blockIdx.x * blockDim.x + threadIdx.x;
    if (i >= total4) return;
    int c4 = (i & 31) * 4;
    float4 z = ((const float4*)Z)[i];
    float4 sc = *(const float4*)&scale[c4];
    float4 sh = *(const float4*)&shift[c4];
    float4 y;
    y.x = fmaxf(fmaf(z.x, sc.x, sh.x), 0.f);
    y.y = fmaxf(fmaf(z.y, sc.y, sh.y), 0.f);
    y.z = fmaxf(fmaf(z.z, sc.z, sh.z), 0.f);
    y.w = fmaxf(fmaf(z.w, sc.w, sh.w), 0.f);
    ((float4*)H)[i] = y;
}

// ---------------- pooling + head ----------------
__global__ void zero_pool_kernel(float* pooled, float* cnt, int ng) {
    int i = blockIdx.x * blockDim.x + threadIdx.x;
    if (i < ng * HID) pooled[i] = 0.f;
    if (i < ng) cnt[i] = 0.f;
}

__global__ void pool_kernel(const float* __restrict__ H, const int* __restrict__ batch,
                            float* __restrict__ pooled, float* __restrict__ cnt, int N) {
    int i = blockIdx.x * blockDim.x + threadIdx.x;  // over N*32 float4s
    if (i >= N * 32) return;
    int n = i >> 5;
    int c4 = (i & 31) * 4;
    int b = batch[n];
    float4 h = ((const float4*)H)[i];
    atomicAdd(&pooled[b * HID + c4 + 0], h.x);
    atomicAdd(&pooled[b * HID + c4 + 1], h.y);
    atomicAdd(&pooled[b * HID + c4 + 2], h.z);
    atomicAdd(&pooled[b * HID + c4 + 3], h.w);
    if ((i & 31) == 0) atomicAdd(&cnt[b], 1.f);
}

__global__ __launch_bounds__(64) void head_kernel(const float* __restrict__ pooled,
                                                  const float* __restrict__ cnt,
                                                  const float* __restrict__ Wh1,
                                                  const float* __restrict__ bh1,
                                                  const float* __restrict__ Wh2,
                                                  const float* __restrict__ bh2,
                                                  float* __restrict__ out, int ng) {
    int g = blockIdx.x;
    if (g >= ng) return;
    int t = threadIdx.x;  // 64
    __shared__ float p[128];
    float c = fmaxf(cnt[g], 1.f);
    p[t] = pooled[g * HID + t] / c;
    p[t + 64] = pooled[g * HID + 64 + t] / c;
    __syncthreads();
    float acc = bh1[t];
    for (int k = 0; k < 128; k++) acc = fmaf(p[k], Wh1[k * 64 + t], acc);
    acc = fmaxf(acc, 0.f);
    float prod = acc * Wh2[t];
    for (int off = 32; off > 0; off >>= 1) prod += __shfl_down(prod, off);
    if (t == 0) out[g] = prod + bh2[0];
}

extern "C" void kernel_launch(void* const* d_in, const int* in_sizes, int n_in,
                              void* d_out, int out_size, void* d_ws, size_t ws_size,
                              hipStream_t stream) {
    const float* x = (const float*)d_in[0];
    const int* ei = (const int*)d_in[1];
    const int* batch = (const int*)d_in[2];
    const float* Wn[3] = {(const float*)d_in[3], (const float*)d_in[8], (const float*)d_in[13]};
    const float* bb[3] = {(const float*)d_in[4], (const float*)d_in[9], (const float*)d_in[14]};
    const float* Wr[3] = {(const float*)d_in[5], (const float*)d_in[10], (const float*)d_in[15]};
    const float* gg[3] = {(const float*)d_in[6], (const float*)d_in[11], (const float*)d_in[16]};
    const float* be[3] = {(const float*)d_in[7], (const float*)d_in[12], (const float*)d_in[17]};
    const float* Wh1 = (const float*)d_in[18];
    const float* bh1 = (const float*)d_in[19];
    const float* Wh2 = (const float*)d_in[20];
    const float* bh2 = (const float*)d_in[21];
    float* out = (float*)d_out;

    const int N = in_sizes[2];      // 50000 nodes
    const int NE = in_sizes[1] / 2; // 800000 edges
    const int NG = out_size;        // 1000 graphs
    const int K0 = in_sizes[0] / N; // 78 input channels

    const int* src = ei;
    const int* dst = ei + NE;

    // workspace carve (256B-aligned chunks)
    char* w = (char*)d_ws;
    auto alloc = [&](size_t bytes) -> void* {
        void* p = (void*)w;
        w += (bytes + 255) & ~(size_t)255;
        return p;
    };
    float* bufA = (float*)alloc((size_t)N * HID * 4);  // U
    float* bufB = (float*)alloc((size_t)N * HID * 4);  // V
    float* bufC = (float*)alloc((size_t)N * HID * 4);  // Z
    float* bufD = (float*)alloc((size_t)N * HID * 4);  // H (layer output)
    int* counts = (int*)alloc((size_t)N * 4);
    int* offsets = (int*)alloc((size_t)(N + 1) * 4);
    int* cursor = (int*)alloc((size_t)N * 4);
    int* esrc = (int*)alloc((size_t)NE * 4);
    double* sums = (double*)alloc(HID * 8);
    double* sumsq = (double*)alloc(HID * 8);
    float* scale = (float*)alloc(HID * 4);
    float* shift = (float*)alloc(HID * 4);
    float* pooled = (float*)alloc((size_t)NG * HID * 4);
    float* cnt = (float*)alloc((size_t)NG * 4);
    (void)ws_size;
    (void)n_in;

    // ---- CSR by dst (built once per call; reused by all 3 layers) ----
    zero_int_kernel<<<(N + 255) / 256, 256, 0, stream>>>(counts, N);
    count_kernel<<<(NE + 255) / 256, 256, 0, stream>>>(dst, counts, NE);
    scan_kernel<<<1, 1024, 0, stream>>>(counts, offsets, N);
    copy_int_kernel<<<(N + 255) / 256, 256, 0, stream>>>(offsets, cursor, N);
    fill_kernel<<<(NE + 255) / 256, 256, 0, stream>>>(src, dst, cursor, esrc, NE);

    // ---- 3 SAGE+BN+ReLU layers ----
    const float* Hin = x;
    int K = K0;
    for (int l = 0; l < 3; l++) {
        gemm_dual_kernel<<<(N + 31) / 32, 256, 0, stream>>>(Hin, Wn[l], Wr[l], bufA, bufB, N, K);
        zero_stats_kernel<<<1, 128, 0, stream>>>(sums, sumsq);
        agg_kernel<<<N, 128, 0, stream>>>(bufA, bufB, bb[l], counts, offsets, esrc, bufC, N);
        stats_kernel<<<512, 256, 0, stream>>>(bufC, sums, sumsq, N);
        bn_finalize_kernel<<<1, 128, 0, stream>>>(sums, sumsq, gg[l], be[l], scale, shift, N);
        int total4 = N * HID / 4;
        bn_relu_kernel<<<(total4 + 255) / 256, 256, 0, stream>>>(bufC, scale, shift, bufD, total4);
        Hin = bufD;
        K = HID;
    }

    // ---- global mean pool + MLP head ----
    zero_pool_kernel<<<(NG * HID + 255) / 256, 256, 0, stream>>>(pooled, cnt, NG);
    pool_kernel<<<(N * 32 + 255) / 256, 256, 0, stream>>>(bufD, batch, pooled, cnt, N);
    head_kernel<<<NG, 64, 0, stream>>>(pooled, cnt, Wh1, bh1, Wh2, bh2, out, NG);
}

// Round 2
// 766.621 us; speedup vs baseline: 1.1319x; 1.1319x over previous
//
#include <hip/hip_runtime.h>
#include <math.h>

#define HID 128

// ---------------- CSR build ----------------
__global__ void zero_int_kernel(int* p, int n) {
    int i = blockIdx.x * blockDim.x + threadIdx.x;
    if (i < n) p[i] = 0;
}

__global__ void count_kernel(const int* __restrict__ dst, int* __restrict__ counts, int ne) {
    int i = blockIdx.x * blockDim.x + threadIdx.x;
    if (i < ne) atomicAdd(&counts[dst[i]], 1);
}

__global__ __launch_bounds__(1024) void scan_kernel(const int* __restrict__ counts,
                                                    int* __restrict__ offsets, int n) {
    __shared__ int part[1024];
    int t = threadIdx.x;
    int chunk = (n + 1023) >> 10;
    int base = t * chunk;
    int s = 0;
    for (int i = 0; i < chunk; i++) {
        int idx = base + i;
        if (idx < n) s += counts[idx];
    }
    part[t] = s;
    __syncthreads();
    for (int off = 1; off < 1024; off <<= 1) {
        int v = 0;
        if (t >= off) v = part[t - off];
        __syncthreads();
        if (t >= off) part[t] += v;
        __syncthreads();
    }
    int run = (t == 0) ? 0 : part[t - 1];
    for (int i = 0; i < chunk; i++) {
        int idx = base + i;
        if (idx < n) {
            offsets[idx] = run;
            run += counts[idx];
        }
    }
}

__global__ void copy_int_kernel(const int* __restrict__ a, int* __restrict__ b, int n) {
    int i = blockIdx.x * blockDim.x + threadIdx.x;
    if (i < n) b[i] = a[i];
}

__global__ void fill_kernel(const int* __restrict__ src, const int* __restrict__ dst,
                            int* __restrict__ cursor, int* __restrict__ esrc, int ne) {
    int i = blockIdx.x * blockDim.x + threadIdx.x;
    if (i < ne) {
        int d = dst[i];
        int pos = atomicAdd(&cursor[d], 1);
        esrc[pos] = src[i];
    }
}

// ---------------- dual GEMM: U = H@Wn, V = H@Wr ----------------
__global__ __launch_bounds__(256) void gemm_dual_kernel(const float* __restrict__ H,
                                                        const float* __restrict__ Wn,
                                                        const float* __restrict__ Wr,
                                                        float* __restrict__ U,
                                                        float* __restrict__ V,
                                                        int N, int K) {
    __shared__ __align__(16) float As[16][32];    // [k][row]
    __shared__ __align__(16) float B1s[16][128];  // [k][col]
    __shared__ __align__(16) float B2s[16][128];
    int tid = threadIdx.x;
    int col_t = tid & 31;
    int row_t = tid >> 5;
    int n0 = blockIdx.x * 32;

    float accU[4][4], accV[4][4];
#pragma unroll
    for (int i = 0; i < 4; i++)
#pragma unroll
        for (int j = 0; j < 4; j++) { accU[i][j] = 0.f; accV[i][j] = 0.f; }

    int lk = tid & 15, lr = tid >> 4;
    int lc = tid & 127, lk0 = tid >> 7;

    for (int kc = 0; kc < K; kc += 16) {
#pragma unroll
        for (int rr = lr; rr < 32; rr += 16) {
            int n = n0 + rr;
            int kk = kc + lk;
            float v = 0.f;
            if (n < N && kk < K) v = H[(size_t)n * K + kk];
            As[lk][rr] = v;
        }
#pragma unroll
        for (int k = lk0; k < 16; k += 2) {
            int kk = kc + k;
            float v1 = 0.f, v2 = 0.f;
            if (kk < K) {
                v1 = Wn[kk * HID + lc];
                v2 = Wr[kk * HID + lc];
            }
            B1s[k][lc] = v1;
            B2s[k][lc] = v2;
        }
        __syncthreads();
#pragma unroll
        for (int k = 0; k < 16; k++) {
            float4 a  = *(const float4*)&As[k][4 * row_t];
            float4 b1 = *(const float4*)&B1s[k][4 * col_t];
            float4 b2 = *(const float4*)&B2s[k][4 * col_t];
            float av[4]  = {a.x, a.y, a.z, a.w};
            float b1v[4] = {b1.x, b1.y, b1.z, b1.w};
            float b2v[4] = {b2.x, b2.y, b2.z, b2.w};
#pragma unroll
            for (int i = 0; i < 4; i++)
#pragma unroll
                for (int j = 0; j < 4; j++) {
                    accU[i][j] = fmaf(av[i], b1v[j], accU[i][j]);
                    accV[i][j] = fmaf(av[i], b2v[j], accV[i][j]);
                }
        }
        __syncthreads();
    }
#pragma unroll
    for (int i = 0; i < 4; i++) {
        int n = n0 + 4 * row_t + i;
        if (n < N) {
            float4 u = {accU[i][0], accU[i][1], accU[i][2], accU[i][3]};
            float4 v = {accV[i][0], accV[i][1], accV[i][2], accV[i][3]};
            *(float4*)&U[(size_t)n * HID + 4 * col_t] = u;
            *(float4*)&V[(size_t)n * HID + 4 * col_t] = v;
        }
    }
}

// ---------------- aggregation: Z[n] = mean_{e->n} U[src_e] + V[n] + b ----------------
__global__ __launch_bounds__(128) void agg_kernel(const float* __restrict__ U,
                                                  const float* __restrict__ V,
                                                  const float* __restrict__ bias,
                                                  const int* __restrict__ counts,
                                                  const int* __restrict__ offsets,
                                                  const int* __restrict__ esrc,
                                                  float* __restrict__ Z, int N) {
    int n = blockIdx.x;
    if (n >= N) return;
    int c = threadIdx.x;
    int deg = counts[n];
    int st = offsets[n];
    float a0 = 0.f, a1 = 0.f, a2 = 0.f, a3 = 0.f;
    int i = 0;
    for (; i + 3 < deg; i += 4) {
        int s0 = esrc[st + i];
        int s1 = esrc[st + i + 1];
        int s2 = esrc[st + i + 2];
        int s3 = esrc[st + i + 3];
        a0 += U[(size_t)s0 * HID + c];
        a1 += U[(size_t)s1 * HID + c];
        a2 += U[(size_t)s2 * HID + c];
        a3 += U[(size_t)s3 * HID + c];
    }
    for (; i < deg; i++) a0 += U[(size_t)esrc[st + i] * HID + c];
    float acc = (a0 + a1) + (a2 + a3);
    float d = (float)(deg > 1 ? deg : 1);
    Z[(size_t)n * HID + c] = acc / d + V[(size_t)n * HID + c] + bias[c];
}

// ---------------- BN stats ----------------
__global__ __launch_bounds__(128) void zero_stats_kernel(double* sums, double* sumsq) {
    int t = threadIdx.x;
    sums[t] = 0.0;
    sumsq[t] = 0.0;
}

__global__ __launch_bounds__(256) void stats_kernel(const float* __restrict__ Z,
                                                    double* __restrict__ sums,
                                                    double* __restrict__ sumsq, int N) {
    int c = threadIdx.x & 127;
    int half = threadIdx.x >> 7;
    int P = (N + gridDim.x - 1) / gridDim.x;
    int n0 = blockIdx.x * P;
    int n1 = n0 + P;
    if (n1 > N) n1 = N;
    float s = 0.f, q = 0.f;
    for (int n = n0 + half; n < n1; n += 2) {
        float z = Z[(size_t)n * HID + c];
        s += z;
        q += z * z;
    }
    __shared__ float bs[256], bq[256];
    bs[threadIdx.x] = s;
    bq[threadIdx.x] = q;
    __syncthreads();
    if (threadIdx.x < 128) {
        double S = (double)bs[threadIdx.x] + (double)bs[threadIdx.x + 128];
        double Q = (double)bq[threadIdx.x] + (double)bq[threadIdx.x + 128];
        atomicAdd(&sums[threadIdx.x], S);
        atomicAdd(&sumsq[threadIdx.x], Q);
    }
}

__global__ __launch_bounds__(128) void bn_finalize_kernel(const double* __restrict__ sums,
                                                          const double* __restrict__ sumsq,
                                                          const float* __restrict__ g,
                                                          const float* __restrict__ be,
                                                          float* __restrict__ scale,
                                                          float* __restrict__ shift, int N) {
    int c = threadIdx.x;
    double mu = sums[c] / (double)N;
    double var = sumsq[c] / (double)N - mu * mu;
    if (var < 0.0) var = 0.0;
    float rs = (float)(1.0 / sqrt(var + 1e-5));
    float sc = g[c] * rs;
    scale[c] = sc;
    shift[c] = be[c] - (float)mu * sc;
}

__global__ __launch_bounds__(256) void bn_relu_kernel(const float* __restrict__ Z,
                                                      const float* __restrict__ scale,
                                                      const float* __restrict__ shift,
                                                      float* __restrict__ H, int total4) {
    int i = blockIdx.x * blockDim.x + threadIdx.x;
    if (i >= total4) return;
    int c4 = (i & 31) * 4;
    float4 z = ((const float4*)Z)[i];
    float4 sc = *(const float4*)&scale[c4];
    float4 sh = *(const float4*)&shift[c4];
    float4 y;
    y.x = fmaxf(fmaf(z.x, sc.x, sh.x), 0.f);
    y.y = fmaxf(fmaf(z.y, sc.y, sh.y), 0.f);
    y.z = fmaxf(fmaf(z.z, sc.z, sh.z), 0.f);
    y.w = fmaxf(fmaf(z.w, sc.w, sh.w), 0.f);
    ((float4*)H)[i] = y;
}

// ---------------- segmented mean pool (batch is sorted) ----------------
// one block (128 threads) per graph; binary-search segment bounds, coalesced sum.
__global__ __launch_bounds__(128) void pool_seg_kernel(const float* __restrict__ H,
                                                       const int* __restrict__ batch,
                                                       float* __restrict__ pooled, int N) {
    int g = blockIdx.x;
    __shared__ int bounds[2];
    if (threadIdx.x < 2) {
        int target = g + threadIdx.x;  // find first index with batch[idx] >= target
        int lo = 0, hi = N;
        while (lo < hi) {
            int mid = (lo + hi) >> 1;
            if (batch[mid] < target) lo = mid + 1;
            else hi = mid;
        }
        bounds[threadIdx.x] = lo;
    }
    __syncthreads();
    int start = bounds[0], end = bounds[1];
    int c = threadIdx.x;
    float s = 0.f;
    for (int n = start; n < end; n++) s += H[(size_t)n * HID + c];
    float cntf = (float)(end - start);
    pooled[(size_t)g * HID + c] = s / fmaxf(cntf, 1.f);
}

// ---------------- MLP head (pooled already means) ----------------
__global__ __launch_bounds__(64) void head_kernel(const float* __restrict__ pooled,
                                                  const float* __restrict__ Wh1,
                                                  const float* __restrict__ bh1,
                                                  const float* __restrict__ Wh2,
                                                  const float* __restrict__ bh2,
                                                  float* __restrict__ out, int ng) {
    int g = blockIdx.x;
    if (g >= ng) return;
    int t = threadIdx.x;
    __shared__ float p[128];
    p[t] = pooled[g * HID + t];
    p[t + 64] = pooled[g * HID + 64 + t];
    __syncthreads();
    float acc = bh1[t];
    for (int k = 0; k < 128; k++) acc = fmaf(p[k], Wh1[k * 64 + t], acc);
    acc = fmaxf(acc, 0.f);
    float prod = acc * Wh2[t];
    for (int off = 32; off > 0; off >>= 1) prod += __shfl_down(prod, off);
    if (t == 0) out[g] = prod + bh2[0];
}

extern "C" void kernel_launch(void* const* d_in, const int* in_sizes, int n_in,
                              void* d_out, int out_size, void* d_ws, size_t ws_size,
                              hipStream_t stream) {
    const float* x = (const float*)d_in[0];
    const int* ei = (const int*)d_in[1];
    const int* batch = (const int*)d_in[2];
    const float* Wn[3] = {(const float*)d_in[3], (const float*)d_in[8], (const float*)d_in[13]};
    const float* bb[3] = {(const float*)d_in[4], (const float*)d_in[9], (const float*)d_in[14]};
    const float* Wr[3] = {(const float*)d_in[5], (const float*)d_in[10], (const float*)d_in[15]};
    const float* gg[3] = {(const float*)d_in[6], (const float*)d_in[11], (const float*)d_in[16]};
    const float* be[3] = {(const float*)d_in[7], (const float*)d_in[12], (const float*)d_in[17]};
    const float* Wh1 = (const float*)d_in[18];
    const float* bh1 = (const float*)d_in[19];
    const float* Wh2 = (const float*)d_in[20];
    const float* bh2 = (const float*)d_in[21];
    float* out = (float*)d_out;

    const int N = in_sizes[2];
    const int NE = in_sizes[1] / 2;
    const int NG = out_size;
    const int K0 = in_sizes[0] / N;

    const int* src = ei;
    const int* dst = ei + NE;

    char* w = (char*)d_ws;
    auto alloc = [&](size_t bytes) -> void* {
        void* p = (void*)w;
        w += (bytes + 255) & ~(size_t)255;
        return p;
    };
    float* bufA = (float*)alloc((size_t)N * HID * 4);  // U
    float* bufB = (float*)alloc((size_t)N * HID * 4);  // V
    float* bufC = (float*)alloc((size_t)N * HID * 4);  // Z
    float* bufD = (float*)alloc((size_t)N * HID * 4);  // H
    int* counts = (int*)alloc((size_t)N * 4);
    int* offsets = (int*)alloc((size_t)(N + 1) * 4);
    int* cursor = (int*)alloc((size_t)N * 4);
    int* esrc = (int*)alloc((size_t)NE * 4);
    double* sums = (double*)alloc(HID * 8);
    double* sumsq = (double*)alloc(HID * 8);
    float* scale = (float*)alloc(HID * 4);
    float* shift = (float*)alloc(HID * 4);
    float* pooled = (float*)alloc((size_t)NG * HID * 4);
    (void)ws_size;
    (void)n_in;

    // ---- CSR by dst ----
    zero_int_kernel<<<(N + 255) / 256, 256, 0, stream>>>(counts, N);
    count_kernel<<<(NE + 255) / 256, 256, 0, stream>>>(dst, counts, NE);
    scan_kernel<<<1, 1024, 0, stream>>>(counts, offsets, N);
    copy_int_kernel<<<(N + 255) / 256, 256, 0, stream>>>(offsets, cursor, N);
    fill_kernel<<<(NE + 255) / 256, 256, 0, stream>>>(src, dst, cursor, esrc, NE);

    // ---- 3 SAGE+BN+ReLU layers ----
    const float* Hin = x;
    int K = K0;
    for (int l = 0; l < 3; l++) {
        gemm_dual_kernel<<<(N + 31) / 32, 256, 0, stream>>>(Hin, Wn[l], Wr[l], bufA, bufB, N, K);
        zero_stats_kernel<<<1, 128, 0, stream>>>(sums, sumsq);
        agg_kernel<<<N, 128, 0, stream>>>(bufA, bufB, bb[l], counts, offsets, esrc, bufC, N);
        stats_kernel<<<512, 256, 0, stream>>>(bufC, sums, sumsq, N);
        bn_finalize_kernel<<<1, 128, 0, stream>>>(sums, sumsq, gg[l], be[l], scale, shift, N);
        int total4 = N * HID / 4;
        bn_relu_kernel<<<(total4 + 255) / 256, 256, 0, stream>>>(bufC, scale, shift, bufD, total4);
        Hin = bufD;
        K = HID;
    }

    // ---- segmented mean pool + MLP head ----
    pool_seg_kernel<<<NG, 128, 0, stream>>>(bufD, batch, pooled, N);
    head_kernel<<<NG, 64, 0, stream>>>(pooled, Wh1, bh1, Wh2, bh2, out, NG);
}

// Round 3
// 685.572 us; speedup vs baseline: 1.2657x; 1.1182x over previous
//
#include <hip/hip_runtime.h>
#include <math.h>

#define HID 128
#define SCB 256  // scan block size

// ---------------- CSR build ----------------
__global__ void zero_int_kernel(int* p, int n) {
    int i = blockIdx.x * blockDim.x + threadIdx.x;
    if (i < n) p[i] = 0;
}

__global__ void count_kernel(const int* __restrict__ dst, int* __restrict__ counts, int ne) {
    int i = blockIdx.x * blockDim.x + threadIdx.x;
    if (i < ne) atomicAdd(&counts[dst[i]], 1);
}

// phase 1: per-block exclusive scan + block totals
__global__ __launch_bounds__(SCB) void scan_blocks_kernel(const int* __restrict__ counts,
                                                          int* __restrict__ offsets,
                                                          int* __restrict__ partials, int n) {
    __shared__ int tmp[SCB];
    int t = threadIdx.x;
    int gid = blockIdx.x * SCB + t;
    int v = (gid < n) ? counts[gid] : 0;
    tmp[t] = v;
    __syncthreads();
    for (int off = 1; off < SCB; off <<= 1) {
        int u = 0;
        if (t >= off) u = tmp[t - off];
        __syncthreads();
        if (t >= off) tmp[t] += u;
        __syncthreads();
    }
    if (gid < n) offsets[gid] = tmp[t] - v;  // exclusive within block
    if (t == SCB - 1) partials[blockIdx.x] = tmp[t];
}

// phase 2: exclusive scan of block partials (nb <= 1024)
__global__ __launch_bounds__(1024) void scan_partials_kernel(int* __restrict__ partials, int nb) {
    __shared__ int tmp[1024];
    int t = threadIdx.x;
    int v = (t < nb) ? partials[t] : 0;
    tmp[t] = v;
    __syncthreads();
    for (int off = 1; off < 1024; off <<= 1) {
        int u = 0;
        if (t >= off) u = tmp[t - off];
        __syncthreads();
        if (t >= off) tmp[t] += u;
        __syncthreads();
    }
    if (t < nb) partials[t] = tmp[t] - v;  // exclusive
}

// phase 3: add block offset; emit offsets and cursor copy
__global__ __launch_bounds__(SCB) void scan_add_kernel(int* __restrict__ offsets,
                                                       const int* __restrict__ partials,
                                                       int* __restrict__ cursor, int n) {
    int gid = blockIdx.x * SCB + threadIdx.x;
    if (gid < n) {
        int v = offsets[gid] + partials[blockIdx.x];
        offsets[gid] = v;
        cursor[gid] = v;
    }
}

__global__ void fill_kernel(const int* __restrict__ src, const int* __restrict__ dst,
                            int* __restrict__ cursor, int* __restrict__ esrc, int ne) {
    int i = blockIdx.x * blockDim.x + threadIdx.x;
    if (i < ne) {
        int d = dst[i];
        int pos = atomicAdd(&cursor[d], 1);
        esrc[pos] = src[i];
    }
}

// ---------------- dual GEMM: U = H@Wn, V = H@Wr ----------------
__global__ __launch_bounds__(256) void gemm_dual_kernel(const float* __restrict__ H,
                                                        const float* __restrict__ Wn,
                                                        const float* __restrict__ Wr,
                                                        float* __restrict__ U,
                                                        float* __restrict__ V,
                                                        int N, int K) {
    __shared__ __align__(16) float As[16][32];    // [k][row]
    __shared__ __align__(16) float B1s[16][128];  // [k][col]
    __shared__ __align__(16) float B2s[16][128];
    int tid = threadIdx.x;
    int col_t = tid & 31;
    int row_t = tid >> 5;
    int n0 = blockIdx.x * 32;

    float accU[4][4], accV[4][4];
#pragma unroll
    for (int i = 0; i < 4; i++)
#pragma unroll
        for (int j = 0; j < 4; j++) { accU[i][j] = 0.f; accV[i][j] = 0.f; }

    int lk = tid & 15, lr = tid >> 4;
    int lc = tid & 127, lk0 = tid >> 7;

    for (int kc = 0; kc < K; kc += 16) {
#pragma unroll
        for (int rr = lr; rr < 32; rr += 16) {
            int n = n0 + rr;
            int kk = kc + lk;
            float v = 0.f;
            if (n < N && kk < K) v = H[(size_t)n * K + kk];
            As[lk][rr] = v;
        }
#pragma unroll
        for (int k = lk0; k < 16; k += 2) {
            int kk = kc + k;
            float v1 = 0.f, v2 = 0.f;
            if (kk < K) {
                v1 = Wn[kk * HID + lc];
                v2 = Wr[kk * HID + lc];
            }
            B1s[k][lc] = v1;
            B2s[k][lc] = v2;
        }
        __syncthreads();
#pragma unroll
        for (int k = 0; k < 16; k++) {
            float4 a  = *(const float4*)&As[k][4 * row_t];
            float4 b1 = *(const float4*)&B1s[k][4 * col_t];
            float4 b2 = *(const float4*)&B2s[k][4 * col_t];
            float av[4]  = {a.x, a.y, a.z, a.w};
            float b1v[4] = {b1.x, b1.y, b1.z, b1.w};
            float b2v[4] = {b2.x, b2.y, b2.z, b2.w};
#pragma unroll
            for (int i = 0; i < 4; i++)
#pragma unroll
                for (int j = 0; j < 4; j++) {
                    accU[i][j] = fmaf(av[i], b1v[j], accU[i][j]);
                    accV[i][j] = fmaf(av[i], b2v[j], accV[i][j]);
                }
        }
        __syncthreads();
    }
#pragma unroll
    for (int i = 0; i < 4; i++) {
        int n = n0 + 4 * row_t + i;
        if (n < N) {
            float4 u = {accU[i][0], accU[i][1], accU[i][2], accU[i][3]};
            float4 v = {accV[i][0], accV[i][1], accV[i][2], accV[i][3]};
            *(float4*)&U[(size_t)n * HID + 4 * col_t] = u;
            *(float4*)&V[(size_t)n * HID + 4 * col_t] = v;
        }
    }
}

// ---------------- aggregation: Z[n] = mean_{e->n} U[src_e] + V[n] + b ----------------
__global__ __launch_bounds__(128) void agg_kernel(const float* __restrict__ U,
                                                  const float* __restrict__ V,
                                                  const float* __restrict__ bias,
                                                  const int* __restrict__ counts,
                                                  const int* __restrict__ offsets,
                                                  const int* __restrict__ esrc,
                                                  float* __restrict__ Z, int N) {
    int n = blockIdx.x;
    if (n >= N) return;
    int c = threadIdx.x;
    int deg = counts[n];
    int st = offsets[n];
    float a0 = 0.f, a1 = 0.f, a2 = 0.f, a3 = 0.f;
    int i = 0;
    for (; i + 3 < deg; i += 4) {
        int s0 = esrc[st + i];
        int s1 = esrc[st + i + 1];
        int s2 = esrc[st + i + 2];
        int s3 = esrc[st + i + 3];
        a0 += U[(size_t)s0 * HID + c];
        a1 += U[(size_t)s1 * HID + c];
        a2 += U[(size_t)s2 * HID + c];
        a3 += U[(size_t)s3 * HID + c];
    }
    for (; i < deg; i++) a0 += U[(size_t)esrc[st + i] * HID + c];
    float acc = (a0 + a1) + (a2 + a3);
    float d = (float)(deg > 1 ? deg : 1);
    Z[(size_t)n * HID + c] = acc / d + V[(size_t)n * HID + c] + bias[c];
}

// ---------------- BN stats ----------------
__global__ __launch_bounds__(128) void zero_stats_kernel(double* sums, double* sumsq) {
    int t = threadIdx.x;
    sums[t] = 0.0;
    sumsq[t] = 0.0;
}

__global__ __launch_bounds__(256) void stats_kernel(const float* __restrict__ Z,
                                                    double* __restrict__ sums,
                                                    double* __restrict__ sumsq, int N) {
    int c = threadIdx.x & 127;
    int half = threadIdx.x >> 7;
    int P = (N + gridDim.x - 1) / gridDim.x;
    int n0 = blockIdx.x * P;
    int n1 = n0 + P;
    if (n1 > N) n1 = N;
    float s = 0.f, q = 0.f;
    for (int n = n0 + half; n < n1; n += 2) {
        float z = Z[(size_t)n * HID + c];
        s += z;
        q += z * z;
    }
    __shared__ float bs[256], bq[256];
    bs[threadIdx.x] = s;
    bq[threadIdx.x] = q;
    __syncthreads();
    if (threadIdx.x < 128) {
        double S = (double)bs[threadIdx.x] + (double)bs[threadIdx.x + 128];
        double Q = (double)bq[threadIdx.x] + (double)bq[threadIdx.x + 128];
        atomicAdd(&sums[threadIdx.x], S);
        atomicAdd(&sumsq[threadIdx.x], Q);
    }
}

__global__ __launch_bounds__(128) void bn_finalize_kernel(const double* __restrict__ sums,
                                                          const double* __restrict__ sumsq,
                                                          const float* __restrict__ g,
                                                          const float* __restrict__ be,
                                                          float* __restrict__ scale,
                                                          float* __restrict__ shift, int N) {
    int c = threadIdx.x;
    double mu = sums[c] / (double)N;
    double var = sumsq[c] / (double)N - mu * mu;
    if (var < 0.0) var = 0.0;
    float rs = (float)(1.0 / sqrt(var + 1e-5));
    float sc = g[c] * rs;
    scale[c] = sc;
    shift[c] = be[c] - (float)mu * sc;
}

__global__ __launch_bounds__(256) void bn_relu_kernel(const float* __restrict__ Z,
                                                      const float* __restrict__ scale,
                                                      const float* __restrict__ shift,
                                                      float* __restrict__ H, int total4) {
    int i = blockIdx.x * blockDim.x + threadIdx.x;
    if (i >= total4) return;
    int c4 = (i & 31) * 4;
    float4 z = ((const float4*)Z)[i];
    float4 sc = *(const float4*)&scale[c4];
    float4 sh = *(const float4*)&shift[c4];
    float4 y;
    y.x = fmaxf(fmaf(z.x, sc.x, sh.x), 0.f);
    y.y = fmaxf(fmaf(z.y, sc.y, sh.y), 0.f);
    y.z = fmaxf(fmaf(z.z, sc.z, sh.z), 0.f);
    y.w = fmaxf(fmaf(z.w, sc.w, sh.w), 0.f);
    ((float4*)H)[i] = y;
}

// ---------------- segmented mean pool (batch is sorted) ----------------
__global__ __launch_bounds__(128) void pool_seg_kernel(const float* __restrict__ H,
                                                       const int* __restrict__ batch,
                                                       float* __restrict__ pooled, int N) {
    int g = blockIdx.x;
    __shared__ int bounds[2];
    if (threadIdx.x < 2) {
        int target = g + threadIdx.x;
        int lo = 0, hi = N;
        while (lo < hi) {
            int mid = (lo + hi) >> 1;
            if (batch[mid] < target) lo = mid + 1;
            else hi = mid;
        }
        bounds[threadIdx.x] = lo;
    }
    __syncthreads();
    int start = bounds[0], end = bounds[1];
    int c = threadIdx.x;
    float s = 0.f;
    for (int n = start; n < end; n++) s += H[(size_t)n * HID + c];
    float cntf = (float)(end - start);
    pooled[(size_t)g * HID + c] = s / fmaxf(cntf, 1.f);
}

// ---------------- MLP head ----------------
__global__ __launch_bounds__(64) void head_kernel(const float* __restrict__ pooled,
                                                  const float* __restrict__ Wh1,
                                                  const float* __restrict__ bh1,
                                                  const float* __restrict__ Wh2,
                                                  const float* __restrict__ bh2,
                                                  float* __restrict__ out, int ng) {
    int g = blockIdx.x;
    if (g >= ng) return;
    int t = threadIdx.x;
    __shared__ float p[128];
    p[t] = pooled[g * HID + t];
    p[t + 64] = pooled[g * HID + 64 + t];
    __syncthreads();
    float acc = bh1[t];
    for (int k = 0; k < 128; k++) acc = fmaf(p[k], Wh1[k * 64 + t], acc);
    acc = fmaxf(acc, 0.f);
    float prod = acc * Wh2[t];
    for (int off = 32; off > 0; off >>= 1) prod += __shfl_down(prod, off);
    if (t == 0) out[g] = prod + bh2[0];
}

extern "C" void kernel_launch(void* const* d_in, const int* in_sizes, int n_in,
                              void* d_out, int out_size, void* d_ws, size_t ws_size,
                              hipStream_t stream) {
    const float* x = (const float*)d_in[0];
    const int* ei = (const int*)d_in[1];
    const int* batch = (const int*)d_in[2];
    const float* Wn[3] = {(const float*)d_in[3], (const float*)d_in[8], (const float*)d_in[13]};
    const float* bb[3] = {(const float*)d_in[4], (const float*)d_in[9], (const float*)d_in[14]};
    const float* Wr[3] = {(const float*)d_in[5], (const float*)d_in[10], (const float*)d_in[15]};
    const float* gg[3] = {(const float*)d_in[6], (const float*)d_in[11], (const float*)d_in[16]};
    const float* be[3] = {(const float*)d_in[7], (const float*)d_in[12], (const float*)d_in[17]};
    const float* Wh1 = (const float*)d_in[18];
    const float* bh1 = (const float*)d_in[19];
    const float* Wh2 = (const float*)d_in[20];
    const float* bh2 = (const float*)d_in[21];
    float* out = (float*)d_out;

    const int N = in_sizes[2];
    const int NE = in_sizes[1] / 2;
    const int NG = out_size;
    const int K0 = in_sizes[0] / N;

    const int* src = ei;
    const int* dst = ei + NE;

    char* w = (char*)d_ws;
    auto alloc = [&](size_t bytes) -> void* {
        void* p = (void*)w;
        w += (bytes + 255) & ~(size_t)255;
        return p;
    };
    float* bufA = (float*)alloc((size_t)N * HID * 4);  // U
    float* bufB = (float*)alloc((size_t)N * HID * 4);  // V
    float* bufC = (float*)alloc((size_t)N * HID * 4);  // Z
    float* bufD = (float*)alloc((size_t)N * HID * 4);  // H
    int* counts = (int*)alloc((size_t)N * 4);
    int* offsets = (int*)alloc((size_t)(N + 1) * 4);
    int* cursor = (int*)alloc((size_t)N * 4);
    int* esrc = (int*)alloc((size_t)NE * 4);
    int* partials = (int*)alloc(1024 * 4);
    double* sums = (double*)alloc(HID * 8);
    double* sumsq = (double*)alloc(HID * 8);
    float* scale = (float*)alloc(HID * 4);
    float* shift = (float*)alloc(HID * 4);
    float* pooled = (float*)alloc((size_t)NG * HID * 4);
    (void)ws_size;
    (void)n_in;

    // ---- CSR by dst ----
    int nscb = (N + SCB - 1) / SCB;  // 196 blocks; scan_partials supports <=1024
    zero_int_kernel<<<(N + 255) / 256, 256, 0, stream>>>(counts, N);
    count_kernel<<<(NE + 255) / 256, 256, 0, stream>>>(dst, counts, NE);
    scan_blocks_kernel<<<nscb, SCB, 0, stream>>>(counts, offsets, partials, N);
    scan_partials_kernel<<<1, 1024, 0, stream>>>(partials, nscb);
    scan_add_kernel<<<nscb, SCB, 0, stream>>>(offsets, partials, cursor, N);
    fill_kernel<<<(NE + 255) / 256, 256, 0, stream>>>(src, dst, cursor, esrc, NE);

    // ---- 3 SAGE+BN+ReLU layers ----
    const float* Hin = x;
    int K = K0;
    for (int l = 0; l < 3; l++) {
        gemm_dual_kernel<<<(N + 31) / 32, 256, 0, stream>>>(Hin, Wn[l], Wr[l], bufA, bufB, N, K);
        zero_stats_kernel<<<1, 128, 0, stream>>>(sums, sumsq);
        agg_kernel<<<N, 128, 0, stream>>>(bufA, bufB, bb[l], counts, offsets, esrc, bufC, N);
        stats_kernel<<<512, 256, 0, stream>>>(bufC, sums, sumsq, N);
        bn_finalize_kernel<<<1, 128, 0, stream>>>(sums, sumsq, gg[l], be[l], scale, shift, N);
        int total4 = N * HID / 4;
        bn_relu_kernel<<<(total4 + 255) / 256, 256, 0, stream>>>(bufC, scale, shift, bufD, total4);
        Hin = bufD;
        K = HID;
    }

    // ---- segmented mean pool + MLP head ----
    pool_seg_kernel<<<NG, 128, 0, stream>>>(bufD, batch, pooled, N);
    head_kernel<<<NG, 64, 0, stream>>>(pooled, Wh1, bh1, Wh2, bh2, out, NG);
}

// Round 4
// 675.327 us; speedup vs baseline: 1.2849x; 1.0152x over previous
//
#include <hip/hip_runtime.h>
#include <hip/hip_bf16.h>
#include <math.h>

#define HID 128
#define SCB 256
#define LSTR 40  // LDS row stride in shorts (80B): 16B-aligned, conflict-free frag reads

typedef short short8 __attribute__((ext_vector_type(8)));
typedef float f32x4 __attribute__((ext_vector_type(4)));

// ---------------- CSR build ----------------
__global__ void zero_int_kernel(int* p, int n) {
    int i = blockIdx.x * blockDim.x + threadIdx.x;
    if (i < n) p[i] = 0;
}

__global__ void count_kernel(const int* __restrict__ dst, int* __restrict__ counts, int ne) {
    int i = blockIdx.x * blockDim.x + threadIdx.x;
    if (i < ne) atomicAdd(&counts[dst[i]], 1);
}

__global__ __launch_bounds__(SCB) void scan_blocks_kernel(const int* __restrict__ counts,
                                                          int* __restrict__ offsets,
                                                          int* __restrict__ partials, int n) {
    __shared__ int tmp[SCB];
    int t = threadIdx.x;
    int gid = blockIdx.x * SCB + t;
    int v = (gid < n) ? counts[gid] : 0;
    tmp[t] = v;
    __syncthreads();
    for (int off = 1; off < SCB; off <<= 1) {
        int u = 0;
        if (t >= off) u = tmp[t - off];
        __syncthreads();
        if (t >= off) tmp[t] += u;
        __syncthreads();
    }
    if (gid < n) offsets[gid] = tmp[t] - v;
    if (t == SCB - 1) partials[blockIdx.x] = tmp[t];
}

__global__ __launch_bounds__(1024) void scan_partials_kernel(int* __restrict__ partials, int nb) {
    __shared__ int tmp[1024];
    int t = threadIdx.x;
    int v = (t < nb) ? partials[t] : 0;
    tmp[t] = v;
    __syncthreads();
    for (int off = 1; off < 1024; off <<= 1) {
        int u = 0;
        if (t >= off) u = tmp[t - off];
        __syncthreads();
        if (t >= off) tmp[t] += u;
        __syncthreads();
    }
    if (t < nb) partials[t] = tmp[t] - v;
}

__global__ __launch_bounds__(SCB) void scan_add_kernel(int* __restrict__ offsets,
                                                       const int* __restrict__ partials,
                                                       int* __restrict__ cursor, int n) {
    int gid = blockIdx.x * SCB + threadIdx.x;
    if (gid < n) {
        int v = offsets[gid] + partials[blockIdx.x];
        offsets[gid] = v;
        cursor[gid] = v;
    }
}

__global__ void fill_kernel(const int* __restrict__ src, const int* __restrict__ dst,
                            int* __restrict__ cursor, int* __restrict__ esrc, int ne) {
    int i = blockIdx.x * blockDim.x + threadIdx.x;
    if (i < ne) {
        int d = dst[i];
        int pos = atomicAdd(&cursor[d], 1);
        esrc[pos] = src[i];
    }
}

// ---------------- fp32 -> bf16 hi/lo converts ----------------
__global__ void convert_x_kernel(const float* __restrict__ x,
                                 unsigned short* __restrict__ xh,
                                 unsigned short* __restrict__ xl,
                                 int N, int K, int Kpad) {
    int i = blockIdx.x * blockDim.x + threadIdx.x;
    if (i >= N * Kpad) return;
    int row = i / Kpad;
    int c = i - row * Kpad;
    float v = (c < K) ? x[(size_t)row * K + c] : 0.f;
    __hip_bfloat16 h = __float2bfloat16(v);
    float hf = __bfloat162float(h);
    __hip_bfloat16 l = __float2bfloat16(v - hf);
    xh[i] = *(unsigned short*)&h;
    xl[i] = *(unsigned short*)&l;
}

// B^T (256 cols x Kpad) from Wn (K x 128) and Wr (K x 128); rows 0-127 = Wn cols, 128-255 = Wr cols
__global__ void convert_w_kernel(const float* __restrict__ Wn, const float* __restrict__ Wr,
                                 unsigned short* __restrict__ bth, unsigned short* __restrict__ btl,
                                 int K, int Kpad) {
    int i = blockIdx.x * blockDim.x + threadIdx.x;
    if (i >= 256 * Kpad) return;
    int ch = i / Kpad;
    int k = i - ch * Kpad;
    float v = 0.f;
    if (k < K) v = (ch < 128) ? Wn[k * 128 + ch] : Wr[k * 128 + (ch - 128)];
    __hip_bfloat16 h = __float2bfloat16(v);
    float hf = __bfloat162float(h);
    __hip_bfloat16 l = __float2bfloat16(v - hf);
    bth[i] = *(unsigned short*)&h;
    btl[i] = *(unsigned short*)&l;
}

// ---------------- MFMA dual GEMM (bf16x3): [U|V] = A @ [Wn|Wr] ----------------
// A as hi/lo bf16 [N][Kpad]; BT as hi/lo bf16 [256][Kpad]. Block: 64 rows x 256 cols, 4 waves.
__global__ __launch_bounds__(256) void gemm_mfma_kernel(
    const unsigned short* __restrict__ A_hi, const unsigned short* __restrict__ A_lo,
    const unsigned short* __restrict__ BT_hi, const unsigned short* __restrict__ BT_lo,
    float* __restrict__ U, float* __restrict__ V, int N, int Kpad) {
    __shared__ unsigned short As_hi[64 * LSTR], As_lo[64 * LSTR];
    __shared__ unsigned short Bs_hi[256 * LSTR], Bs_lo[256 * LSTR];
    int tid = threadIdx.x;
    int lane = tid & 63;
    int w = tid >> 6;        // wave 0..3 -> col strip
    int q = lane >> 4;       // quad 0..3
    int m = lane & 15;

    int n0 = blockIdx.x * 64;

    f32x4 acc[4][4];
#pragma unroll
    for (int r = 0; r < 4; r++)
#pragma unroll
        for (int c = 0; c < 4; c++) acc[r][c] = (f32x4){0.f, 0.f, 0.f, 0.f};

    // staging coords: per wave, 16 rows x 4 chunks; lane -> (row=m, chunk=q) keeps
    // ds_write octets on distinct banks (stride 40 shorts, 5*r+c distinct mod 8)
    int sr_a = 16 * w + m;          // A tile row 0..63
    int arow = n0 + sr_a;
    if (arow >= N) arow = N - 1;    // clamp: garbage rows masked at store

    int ksteps = Kpad >> 5;
    for (int ks = 0; ks < ksteps; ks++) {
        int ko = ks * 32 + q * 8;   // short offset within a row
        uint4 va_hi = *(const uint4*)(A_hi + (size_t)arow * Kpad + ko);
        uint4 va_lo = *(const uint4*)(A_lo + (size_t)arow * Kpad + ko);
        uint4 vb_hi[4], vb_lo[4];
#pragma unroll
        for (int j = 0; j < 4; j++) {
            int brow = 16 * (w + 4 * j) + m;
            vb_hi[j] = *(const uint4*)(BT_hi + (size_t)brow * Kpad + ko);
            vb_lo[j] = *(const uint4*)(BT_lo + (size_t)brow * Kpad + ko);
        }
        __syncthreads();
        *(uint4*)&As_hi[sr_a * LSTR + q * 8] = va_hi;
        *(uint4*)&As_lo[sr_a * LSTR + q * 8] = va_lo;
#pragma unroll
        for (int j = 0; j < 4; j++) {
            int brow = 16 * (w + 4 * j) + m;
            *(uint4*)&Bs_hi[brow * LSTR + q * 8] = vb_hi[j];
            *(uint4*)&Bs_lo[brow * LSTR + q * 8] = vb_lo[j];
        }
        __syncthreads();
        short8 ah[4], al[4], bh[4], bl[4];
#pragma unroll
        for (int r = 0; r < 4; r++) {
            int row = 16 * r + m;
            ah[r] = __builtin_bit_cast(short8, *(uint4*)&As_hi[row * LSTR + q * 8]);
            al[r] = __builtin_bit_cast(short8, *(uint4*)&As_lo[row * LSTR + q * 8]);
        }
#pragma unroll
        for (int c = 0; c < 4; c++) {
            int col = 64 * w + 16 * c + m;
            bh[c] = __builtin_bit_cast(short8, *(uint4*)&Bs_hi[col * LSTR + q * 8]);
            bl[c] = __builtin_bit_cast(short8, *(uint4*)&Bs_lo[col * LSTR + q * 8]);
        }
#pragma unroll
        for (int r = 0; r < 4; r++)
#pragma unroll
            for (int c = 0; c < 4; c++) {
                acc[r][c] = __builtin_amdgcn_mfma_f32_16x16x32_bf16(ah[r], bh[c], acc[r][c], 0, 0, 0);
                acc[r][c] = __builtin_amdgcn_mfma_f32_16x16x32_bf16(ah[r], bl[c], acc[r][c], 0, 0, 0);
                acc[r][c] = __builtin_amdgcn_mfma_f32_16x16x32_bf16(al[r], bh[c], acc[r][c], 0, 0, 0);
            }
    }
    // C/D: col = lane&15, row = quad*4 + reg  [m89-verified]
    float* Out = (w < 2) ? U : V;
    int colbase = (w & 1) * 64;
#pragma unroll
    for (int r = 0; r < 4; r++)
#pragma unroll
        for (int c = 0; c < 4; c++) {
            int col = colbase + 16 * c + m;
#pragma unroll
            for (int i = 0; i < 4; i++) {
                int row = n0 + 16 * r + 4 * q + i;
                if (row < N) Out[(size_t)row * HID + col] = acc[r][c][i];
            }
        }
}

// ---------------- aggregation: Z[n] = mean_{e->n} U[src_e] + V[n] + b ----------------
// NOTE: Z may alias V (row-local read-then-write) -> no __restrict__ on V/Z.
__global__ __launch_bounds__(128) void agg_kernel(const float* __restrict__ U,
                                                  const float* V,
                                                  const float* __restrict__ bias,
                                                  const int* __restrict__ counts,
                                                  const int* __restrict__ offsets,
                                                  const int* __restrict__ esrc,
                                                  float* Z, int N) {
    int n = blockIdx.x;
    if (n >= N) return;
    int c = threadIdx.x;
    int deg = counts[n];
    int st = offsets[n];
    float a0 = 0.f, a1 = 0.f, a2 = 0.f, a3 = 0.f;
    int i = 0;
    for (; i + 3 < deg; i += 4) {
        int s0 = esrc[st + i];
        int s1 = esrc[st + i + 1];
        int s2 = esrc[st + i + 2];
        int s3 = esrc[st + i + 3];
        a0 += U[(size_t)s0 * HID + c];
        a1 += U[(size_t)s1 * HID + c];
        a2 += U[(size_t)s2 * HID + c];
        a3 += U[(size_t)s3 * HID + c];
    }
    for (; i < deg; i++) a0 += U[(size_t)esrc[st + i] * HID + c];
    float acc = (a0 + a1) + (a2 + a3);
    float d = (float)(deg > 1 ? deg : 1);
    float vv = V[(size_t)n * HID + c];
    Z[(size_t)n * HID + c] = acc / d + vv + bias[c];
}

// ---------------- BN stats ----------------
__global__ __launch_bounds__(128) void zero_stats_kernel(double* sums, double* sumsq) {
    int t = threadIdx.x;
    sums[t] = 0.0;
    sumsq[t] = 0.0;
}

__global__ __launch_bounds__(256) void stats_kernel(const float* __restrict__ Z,
                                                    double* __restrict__ sums,
                                                    double* __restrict__ sumsq, int N) {
    int c = threadIdx.x & 127;
    int half = threadIdx.x >> 7;
    int P = (N + gridDim.x - 1) / gridDim.x;
    int n0 = blockIdx.x * P;
    int n1 = n0 + P;
    if (n1 > N) n1 = N;
    float s = 0.f, q = 0.f;
    for (int n = n0 + half; n < n1; n += 2) {
        float z = Z[(size_t)n * HID + c];
        s += z;
        q += z * z;
    }
    __shared__ float bs[256], bq[256];
    bs[threadIdx.x] = s;
    bq[threadIdx.x] = q;
    __syncthreads();
    if (threadIdx.x < 128) {
        double S = (double)bs[threadIdx.x] + (double)bs[threadIdx.x + 128];
        double Q = (double)bq[threadIdx.x] + (double)bq[threadIdx.x + 128];
        atomicAdd(&sums[threadIdx.x], S);
        atomicAdd(&sumsq[threadIdx.x], Q);
    }
}

__global__ __launch_bounds__(128) void bn_finalize_kernel(const double* __restrict__ sums,
                                                          const double* __restrict__ sumsq,
                                                          const float* __restrict__ g,
                                                          const float* __restrict__ be,
                                                          float* __restrict__ scale,
                                                          float* __restrict__ shift, int N) {
    int c = threadIdx.x;
    double mu = sums[c] / (double)N;
    double var = sumsq[c] / (double)N - mu * mu;
    if (var < 0.0) var = 0.0;
    float rs = (float)(1.0 / sqrt(var + 1e-5));
    float sc = g[c] * rs;
    scale[c] = sc;
    shift[c] = be[c] - (float)mu * sc;
}

// layers 0,1: BN+ReLU and emit bf16 hi/lo for the next GEMM
__global__ __launch_bounds__(256) void bn_relu_bf16_kernel(const float* __restrict__ Z,
                                                           const float* __restrict__ scale,
                                                           const float* __restrict__ shift,
                                                           unsigned short* __restrict__ Hh,
                                                           unsigned short* __restrict__ Hl,
                                                           int total4) {
    int i = blockIdx.x * blockDim.x + threadIdx.x;
    if (i >= total4) return;
    int c4 = (i & 31) * 4;
    float4 z = ((const float4*)Z)[i];
    float4 sc = *(const float4*)&scale[c4];
    float4 sh = *(const float4*)&shift[c4];
    float y[4];
    y[0] = fmaxf(fmaf(z.x, sc.x, sh.x), 0.f);
    y[1] = fmaxf(fmaf(z.y, sc.y, sh.y), 0.f);
    y[2] = fmaxf(fmaf(z.z, sc.z, sh.z), 0.f);
    y[3] = fmaxf(fmaf(z.w, sc.w, sh.w), 0.f);
    ushort4 vh, vl;
    unsigned short* ph = (unsigned short*)&vh;
    unsigned short* pl = (unsigned short*)&vl;
#pragma unroll
    for (int j = 0; j < 4; j++) {
        __hip_bfloat16 h = __float2bfloat16(y[j]);
        float hf = __bfloat162float(h);
        __hip_bfloat16 l = __float2bfloat16(y[j] - hf);
        ph[j] = *(unsigned short*)&h;
        pl[j] = *(unsigned short*)&l;
    }
    ((ushort4*)Hh)[i] = vh;
    ((ushort4*)Hl)[i] = vl;
}

// layer 2: BN+ReLU to fp32 (for pooling)
__global__ __launch_bounds__(256) void bn_relu_f32_kernel(const float* __restrict__ Z,
                                                          const float* __restrict__ scale,
                                                          const float* __restrict__ shift,
                                                          float* __restrict__ H, int total4) {
    int i = blockIdx.x * blockDim.x + threadIdx.x;
    if (i >= total4) return;
    int c4 = (i & 31) * 4;
    float4 z = ((const float4*)Z)[i];
    float4 sc = *(const float4*)&scale[c4];
    float4 sh = *(const float4*)&shift[c4];
    float4 y;
    y.x = fmaxf(fmaf(z.x, sc.x, sh.x), 0.f);
    y.y = fmaxf(fmaf(z.y, sc.y, sh.y), 0.f);
    y.z = fmaxf(fmaf(z.z, sc.z, sh.z), 0.f);
    y.w = fmaxf(fmaf(z.w, sc.w, sh.w), 0.f);
    ((float4*)H)[i] = y;
}

// ---------------- segmented mean pool (batch sorted) ----------------
__global__ __launch_bounds__(128) void pool_seg_kernel(const float* __restrict__ H,
                                                       const int* __restrict__ batch,
                                                       float* __restrict__ pooled, int N) {
    int g = blockIdx.x;
    __shared__ int bounds[2];
    if (threadIdx.x < 2) {
        int target = g + threadIdx.x;
        int lo = 0, hi = N;
        while (lo < hi) {
            int mid = (lo + hi) >> 1;
            if (batch[mid] < target) lo = mid + 1;
            else hi = mid;
        }
        bounds[threadIdx.x] = lo;
    }
    __syncthreads();
    int start = bounds[0], end = bounds[1];
    int c = threadIdx.x;
    float s = 0.f;
    for (int n = start; n < end; n++) s += H[(size_t)n * HID + c];
    float cntf = (float)(end - start);
    pooled[(size_t)g * HID + c] = s / fmaxf(cntf, 1.f);
}

// ---------------- MLP head ----------------
__global__ __launch_bounds__(64) void head_kernel(const float* __restrict__ pooled,
                                                  const float* __restrict__ Wh1,
                                                  const float* __restrict__ bh1,
                                                  const float* __restrict__ Wh2,
                                                  const float* __restrict__ bh2,
                                                  float* __restrict__ out, int ng) {
    int g = blockIdx.x;
    if (g >= ng) return;
    int t = threadIdx.x;
    __shared__ float p[128];
    p[t] = pooled[g * HID + t];
    p[t + 64] = pooled[g * HID + 64 + t];
    __syncthreads();
    float acc = bh1[t];
    for (int k = 0; k < 128; k++) acc = fmaf(p[k], Wh1[k * 64 + t], acc);
    acc = fmaxf(acc, 0.f);
    float prod = acc * Wh2[t];
    for (int off = 32; off > 0; off >>= 1) prod += __shfl_down(prod, off);
    if (t == 0) out[g] = prod + bh2[0];
}

extern "C" void kernel_launch(void* const* d_in, const int* in_sizes, int n_in,
                              void* d_out, int out_size, void* d_ws, size_t ws_size,
                              hipStream_t stream) {
    const float* x = (const float*)d_in[0];
    const int* ei = (const int*)d_in[1];
    const int* batch = (const int*)d_in[2];
    const float* Wn[3] = {(const float*)d_in[3], (const float*)d_in[8], (const float*)d_in[13]};
    const float* bb[3] = {(const float*)d_in[4], (const float*)d_in[9], (const float*)d_in[14]};
    const float* Wr[3] = {(const float*)d_in[5], (const float*)d_in[10], (const float*)d_in[15]};
    const float* gg[3] = {(const float*)d_in[6], (const float*)d_in[11], (const float*)d_in[16]};
    const float* be[3] = {(const float*)d_in[7], (const float*)d_in[12], (const float*)d_in[17]};
    const float* Wh1 = (const float*)d_in[18];
    const float* bh1 = (const float*)d_in[19];
    const float* Wh2 = (const float*)d_in[20];
    const float* bh2 = (const float*)d_in[21];
    float* out = (float*)d_out;

    const int N = in_sizes[2];       // 50000
    const int NE = in_sizes[1] / 2;  // 800000
    const int NG = out_size;         // 1000
    const int K0 = in_sizes[0] / N;  // 78
    const int K0pad = ((K0 + 31) / 32) * 32;  // 96

    const int* src = ei;
    const int* dst = ei + NE;

    char* w = (char*)d_ws;
    auto alloc = [&](size_t bytes) -> void* {
        void* p = (void*)w;
        w += (bytes + 255) & ~(size_t)255;
        return p;
    };
    float* bufU = (float*)alloc((size_t)N * HID * 4);
    float* bufV = (float*)alloc((size_t)N * HID * 4);  // also Z (aliased in agg)
    unsigned short* xh = (unsigned short*)alloc((size_t)N * K0pad * 2);
    unsigned short* xl = (unsigned short*)alloc((size_t)N * K0pad * 2);
    unsigned short* Hh = (unsigned short*)alloc((size_t)N * HID * 2);
    unsigned short* Hl = (unsigned short*)alloc((size_t)N * HID * 2);
    unsigned short* BTh[3];
    unsigned short* BTl[3];
    BTh[0] = (unsigned short*)alloc((size_t)256 * K0pad * 2);
    BTl[0] = (unsigned short*)alloc((size_t)256 * K0pad * 2);
    BTh[1] = (unsigned short*)alloc((size_t)256 * HID * 2);
    BTl[1] = (unsigned short*)alloc((size_t)256 * HID * 2);
    BTh[2] = (unsigned short*)alloc((size_t)256 * HID * 2);
    BTl[2] = (unsigned short*)alloc((size_t)256 * HID * 2);
    int* counts = (int*)alloc((size_t)N * 4);
    int* offsets = (int*)alloc((size_t)(N + 1) * 4);
    int* cursor = (int*)alloc((size_t)N * 4);
    int* esrc = (int*)alloc((size_t)NE * 4);
    int* partials = (int*)alloc(1024 * 4);
    double* sums = (double*)alloc(HID * 8);
    double* sumsq = (double*)alloc(HID * 8);
    float* scale = (float*)alloc(HID * 4);
    float* shift = (float*)alloc(HID * 4);
    float* pooled = (float*)alloc((size_t)NG * HID * 4);
    (void)ws_size;
    (void)n_in;

    // ---- CSR by dst ----
    int nscb = (N + SCB - 1) / SCB;
    zero_int_kernel<<<(N + 255) / 256, 256, 0, stream>>>(counts, N);
    count_kernel<<<(NE + 255) / 256, 256, 0, stream>>>(dst, counts, NE);
    scan_blocks_kernel<<<nscb, SCB, 0, stream>>>(counts, offsets, partials, N);
    scan_partials_kernel<<<1, 1024, 0, stream>>>(partials, nscb);
    scan_add_kernel<<<nscb, SCB, 0, stream>>>(offsets, partials, cursor, N);
    fill_kernel<<<(NE + 255) / 256, 256, 0, stream>>>(src, dst, cursor, esrc, NE);

    // ---- converts ----
    convert_x_kernel<<<((size_t)N * K0pad + 255) / 256, 256, 0, stream>>>(x, xh, xl, N, K0, K0pad);
    convert_w_kernel<<<(256 * K0pad + 255) / 256, 256, 0, stream>>>(Wn[0], Wr[0], BTh[0], BTl[0], K0, K0pad);
    convert_w_kernel<<<(256 * HID + 255) / 256, 256, 0, stream>>>(Wn[1], Wr[1], BTh[1], BTl[1], HID, HID);
    convert_w_kernel<<<(256 * HID + 255) / 256, 256, 0, stream>>>(Wn[2], Wr[2], BTh[2], BTl[2], HID, HID);

    // ---- 3 SAGE+BN+ReLU layers ----
    int gblocks = (N + 63) / 64;
    int total4 = N * HID / 4;
    for (int l = 0; l < 3; l++) {
        const unsigned short* Ah = (l == 0) ? xh : Hh;
        const unsigned short* Al = (l == 0) ? xl : Hl;
        int Kpad = (l == 0) ? K0pad : HID;
        gemm_mfma_kernel<<<gblocks, 256, 0, stream>>>(Ah, Al, BTh[l], BTl[l], bufU, bufV, N, Kpad);
        zero_stats_kernel<<<1, 128, 0, stream>>>(sums, sumsq);
        agg_kernel<<<N, 128, 0, stream>>>(bufU, bufV, bb[l], counts, offsets, esrc, bufV, N);
        stats_kernel<<<512, 256, 0, stream>>>(bufV, sums, sumsq, N);
        bn_finalize_kernel<<<1, 128, 0, stream>>>(sums, sumsq, gg[l], be[l], scale, shift, N);
        if (l < 2) {
            bn_relu_bf16_kernel<<<(total4 + 255) / 256, 256, 0, stream>>>(bufV, scale, shift, Hh, Hl, total4);
        } else {
            bn_relu_f32_kernel<<<(total4 + 255) / 256, 256, 0, stream>>>(bufV, scale, shift, bufU, total4);
        }
    }

    // ---- segmented mean pool + MLP head ----
    pool_seg_kernel<<<NG, 128, 0, stream>>>(bufU, batch, pooled, N);
    head_kernel<<<NG, 64, 0, stream>>>(pooled, Wh1, bh1, Wh2, bh2, out, NG);
}

// Round 5
// 674.761 us; speedup vs baseline: 1.2860x; 1.0008x over previous
//
#include <hip/hip_runtime.h>
#include <hip/hip_bf16.h>
#include <math.h>

#define HID 128
#define SCB 256

typedef short short8 __attribute__((ext_vector_type(8)));
typedef float f32x4 __attribute__((ext_vector_type(4)));

// ---------------- CSR build ----------------
__global__ void zero_int_kernel(int* p, int n) {
    int i = blockIdx.x * blockDim.x + threadIdx.x;
    if (i < n) p[i] = 0;
}

__global__ void count_kernel(const int* __restrict__ dst, int* __restrict__ counts, int ne) {
    int i = blockIdx.x * blockDim.x + threadIdx.x;
    if (i < ne) atomicAdd(&counts[dst[i]], 1);
}

__global__ __launch_bounds__(SCB) void scan_blocks_kernel(const int* __restrict__ counts,
                                                          int* __restrict__ offsets,
                                                          int* __restrict__ partials, int n) {
    __shared__ int tmp[SCB];
    int t = threadIdx.x;
    int gid = blockIdx.x * SCB + t;
    int v = (gid < n) ? counts[gid] : 0;
    tmp[t] = v;
    __syncthreads();
    for (int off = 1; off < SCB; off <<= 1) {
        int u = 0;
        if (t >= off) u = tmp[t - off];
        __syncthreads();
        if (t >= off) tmp[t] += u;
        __syncthreads();
    }
    if (gid < n) offsets[gid] = tmp[t] - v;
    if (t == SCB - 1) partials[blockIdx.x] = tmp[t];
}

__global__ __launch_bounds__(1024) void scan_partials_kernel(int* __restrict__ partials, int nb) {
    __shared__ int tmp[1024];
    int t = threadIdx.x;
    int v = (t < nb) ? partials[t] : 0;
    tmp[t] = v;
    __syncthreads();
    for (int off = 1; off < 1024; off <<= 1) {
        int u = 0;
        if (t >= off) u = tmp[t - off];
        __syncthreads();
        if (t >= off) tmp[t] += u;
        __syncthreads();
    }
    if (t < nb) partials[t] = tmp[t] - v;
}

__global__ __launch_bounds__(SCB) void scan_add_kernel(int* __restrict__ offsets,
                                                       const int* __restrict__ partials,
                                                       int* __restrict__ cursor, int n) {
    int gid = blockIdx.x * SCB + threadIdx.x;
    if (gid < n) {
        int v = offsets[gid] + partials[blockIdx.x];
        offsets[gid] = v;
        cursor[gid] = v;
    }
}

__global__ void fill_kernel(const int* __restrict__ src, const int* __restrict__ dst,
                            int* __restrict__ cursor, int* __restrict__ esrc, int ne) {
    int i = blockIdx.x * blockDim.x + threadIdx.x;
    if (i < ne) {
        int d = dst[i];
        int pos = atomicAdd(&cursor[d], 1);
        esrc[pos] = src[i];
    }
}

// ---------------- fp32 -> bf16 hi/lo converts ----------------
__global__ void convert_x_kernel(const float* __restrict__ x,
                                 unsigned short* __restrict__ xh,
                                 unsigned short* __restrict__ xl,
                                 int N, int K, int Kpad) {
    int i = blockIdx.x * blockDim.x + threadIdx.x;
    if (i >= N * Kpad) return;
    int row = i / Kpad;
    int c = i - row * Kpad;
    float v = (c < K) ? x[(size_t)row * K + c] : 0.f;
    __hip_bfloat16 h = __float2bfloat16(v);
    float hf = __bfloat162float(h);
    __hip_bfloat16 l = __float2bfloat16(v - hf);
    xh[i] = *(unsigned short*)&h;
    xl[i] = *(unsigned short*)&l;
}

// B^T (256 cols x Kpad) from Wn (K x 128) and Wr (K x 128)
__global__ void convert_w_kernel(const float* __restrict__ Wn, const float* __restrict__ Wr,
                                 unsigned short* __restrict__ bth, unsigned short* __restrict__ btl,
                                 int K, int Kpad) {
    int i = blockIdx.x * blockDim.x + threadIdx.x;
    if (i >= 256 * Kpad) return;
    int ch = i / Kpad;
    int k = i - ch * Kpad;
    float v = 0.f;
    if (k < K) v = (ch < 128) ? Wn[k * 128 + ch] : Wr[k * 128 + (ch - 128)];
    __hip_bfloat16 h = __float2bfloat16(v);
    float hf = __bfloat162float(h);
    __hip_bfloat16 l = __float2bfloat16(v - hf);
    bth[i] = *(unsigned short*)&h;
    btl[i] = *(unsigned short*)&l;
}

// ---------------- LDS-free MFMA dual GEMM (bf16x3): [U|V] = A @ [Wn|Wr] ----------------
// Fragments load DIRECTLY from global in MFMA A/B layout (16B per lane). No LDS, no barriers.
__global__ __launch_bounds__(256) void gemm_mfma_kernel(
    const unsigned short* __restrict__ A_hi, const unsigned short* __restrict__ A_lo,
    const unsigned short* __restrict__ BT_hi, const unsigned short* __restrict__ BT_lo,
    float* __restrict__ U, float* __restrict__ V, int N, int Kpad) {
    int tid = threadIdx.x;
    int lane = tid & 63;
    int w = tid >> 6;        // wave 0..3
    int q = lane >> 4;       // quad 0..3
    int m = lane & 15;

    int n0 = blockIdx.x * 64;

    f32x4 acc[4][4];
#pragma unroll
    for (int r = 0; r < 4; r++)
#pragma unroll
        for (int c = 0; c < 4; c++) acc[r][c] = (f32x4){0.f, 0.f, 0.f, 0.f};

    size_t abase[4], bbase[4];
#pragma unroll
    for (int r = 0; r < 4; r++) {
        int row = n0 + 16 * r + m;
        if (row >= N) row = N - 1;  // dup-load; stores masked
        abase[r] = (size_t)row * Kpad;
    }
#pragma unroll
    for (int c = 0; c < 4; c++) bbase[c] = (size_t)(64 * w + 16 * c + m) * Kpad;

    int ksteps = Kpad >> 5;
    for (int ks = 0; ks < ksteps; ks++) {
        int ko = ks * 32 + q * 8;
        short8 ah[4], al[4], bh[4], bl[4];
#pragma unroll
        for (int r = 0; r < 4; r++) {
            ah[r] = __builtin_bit_cast(short8, *(const uint4*)(A_hi + abase[r] + ko));
            al[r] = __builtin_bit_cast(short8, *(const uint4*)(A_lo + abase[r] + ko));
        }
#pragma unroll
        for (int c = 0; c < 4; c++) {
            bh[c] = __builtin_bit_cast(short8, *(const uint4*)(BT_hi + bbase[c] + ko));
            bl[c] = __builtin_bit_cast(short8, *(const uint4*)(BT_lo + bbase[c] + ko));
        }
#pragma unroll
        for (int r = 0; r < 4; r++)
#pragma unroll
            for (int c = 0; c < 4; c++) {
                acc[r][c] = __builtin_amdgcn_mfma_f32_16x16x32_bf16(ah[r], bh[c], acc[r][c], 0, 0, 0);
                acc[r][c] = __builtin_amdgcn_mfma_f32_16x16x32_bf16(ah[r], bl[c], acc[r][c], 0, 0, 0);
                acc[r][c] = __builtin_amdgcn_mfma_f32_16x16x32_bf16(al[r], bh[c], acc[r][c], 0, 0, 0);
            }
    }
    // C/D: col = lane&15, row = quad*4 + reg  [m89-verified]
    float* Out = (w < 2) ? U : V;
    int colbase = (w & 1) * 64;
#pragma unroll
    for (int r = 0; r < 4; r++)
#pragma unroll
        for (int c = 0; c < 4; c++) {
            int col = colbase + 16 * c + m;
#pragma unroll
            for (int i = 0; i < 4; i++) {
                int row = n0 + 16 * r + 4 * q + i;
                if (row < N) Out[(size_t)row * HID + col] = acc[r][c][i];
            }
        }
}

// ---------------- aggregation: Z[n] = mean_{e->n} U[src_e] + V[n] + b ----------------
// 8 dst nodes per 256-thread block; 32 lanes x float4 per row. Z aliases V -> no restrict.
__global__ __launch_bounds__(256) void agg_kernel(const float* __restrict__ U,
                                                  const float* V,
                                                  const float* __restrict__ bias,
                                                  const int* __restrict__ counts,
                                                  const int* __restrict__ offsets,
                                                  const int* __restrict__ esrc,
                                                  float* Z, int N) {
    int grp = threadIdx.x >> 5;
    int l32 = threadIdx.x & 31;
    int n = blockIdx.x * 8 + grp;
    if (n >= N) return;
    int deg = counts[n];
    int st = offsets[n];
    const f32x4* U4 = (const f32x4*)U;
    f32x4 a0 = {0,0,0,0}, a1 = {0,0,0,0}, a2 = {0,0,0,0}, a3 = {0,0,0,0};
    int i = 0;
    for (; i + 3 < deg; i += 4) {
        int s0 = esrc[st + i];
        int s1 = esrc[st + i + 1];
        int s2 = esrc[st + i + 2];
        int s3 = esrc[st + i + 3];
        a0 += U4[(size_t)s0 * 32 + l32];
        a1 += U4[(size_t)s1 * 32 + l32];
        a2 += U4[(size_t)s2 * 32 + l32];
        a3 += U4[(size_t)s3 * 32 + l32];
    }
    for (; i < deg; i++) a0 += U4[(size_t)esrc[st + i] * 32 + l32];
    f32x4 acc = (a0 + a1) + (a2 + a3);
    float d = (float)(deg > 1 ? deg : 1);
    f32x4 vv = ((const f32x4*)V)[(size_t)n * 32 + l32];
    f32x4 bb = ((const f32x4*)bias)[l32];
    ((f32x4*)Z)[(size_t)n * 32 + l32] = acc / d + vv + bb;
}

// ---------------- BN stats ----------------
// zero all 3 layers' stat buffers at once (3 * 2 * 128 doubles)
__global__ __launch_bounds__(256) void zero_stats_all_kernel(double* stats) {
    int t = blockIdx.x * blockDim.x + threadIdx.x;
    if (t < 3 * 2 * HID) stats[t] = 0.0;
}

__global__ __launch_bounds__(256) void stats_kernel(const float* __restrict__ Z,
                                                    double* __restrict__ sums,
                                                    double* __restrict__ sumsq, int N) {
    int t = threadIdx.x;
    int cq = t & 31;   // channel quad
    int rg = t >> 5;   // row group 0..7
    const f32x4* Z4 = (const f32x4*)Z;
    f32x4 s = {0,0,0,0}, q = {0,0,0,0};
    for (int n = blockIdx.x * 8 + rg; n < N; n += gridDim.x * 8) {
        f32x4 z = Z4[(size_t)n * 32 + cq];
        s += z;
        q += z * z;
    }
    __shared__ f32x4 bs[256], bq[256];
    bs[t] = s;
    bq[t] = q;
    __syncthreads();
    for (int off = 4; off > 0; off >>= 1) {
        if (rg < off) {
            bs[t] += bs[t + off * 32];
            bq[t] += bq[t + off * 32];
        }
        __syncthreads();
    }
    if (t < 32) {
        f32x4 S = bs[t], Q = bq[t];
#pragma unroll
        for (int j = 0; j < 4; j++) {
            atomicAdd(&sums[4 * t + j], (double)S[j]);
            atomicAdd(&sumsq[4 * t + j], (double)Q[j]);
        }
    }
}

__global__ __launch_bounds__(128) void bn_finalize_kernel(const double* __restrict__ sums,
                                                          const double* __restrict__ sumsq,
                                                          const float* __restrict__ g,
                                                          const float* __restrict__ be,
                                                          float* __restrict__ scale,
                                                          float* __restrict__ shift, int N) {
    int c = threadIdx.x;
    double mu = sums[c] / (double)N;
    double var = sumsq[c] / (double)N - mu * mu;
    if (var < 0.0) var = 0.0;
    float rs = (float)(1.0 / sqrt(var + 1e-5));
    float sc = g[c] * rs;
    scale[c] = sc;
    shift[c] = be[c] - (float)mu * sc;
}

// layers 0,1: BN+ReLU and emit bf16 hi/lo for the next GEMM
__global__ __launch_bounds__(256) void bn_relu_bf16_kernel(const float* __restrict__ Z,
                                                           const float* __restrict__ scale,
                                                           const float* __restrict__ shift,
                                                           unsigned short* __restrict__ Hh,
                                                           unsigned short* __restrict__ Hl,
                                                           int total4) {
    int i = blockIdx.x * blockDim.x + threadIdx.x;
    if (i >= total4) return;
    int c4 = (i & 31) * 4;
    float4 z = ((const float4*)Z)[i];
    float4 sc = *(const float4*)&scale[c4];
    float4 sh = *(const float4*)&shift[c4];
    float y[4];
    y[0] = fmaxf(fmaf(z.x, sc.x, sh.x), 0.f);
    y[1] = fmaxf(fmaf(z.y, sc.y, sh.y), 0.f);
    y[2] = fmaxf(fmaf(z.z, sc.z, sh.z), 0.f);
    y[3] = fmaxf(fmaf(z.w, sc.w, sh.w), 0.f);
    ushort4 vh, vl;
    unsigned short* ph = (unsigned short*)&vh;
    unsigned short* pl = (unsigned short*)&vl;
#pragma unroll
    for (int j = 0; j < 4; j++) {
        __hip_bfloat16 h = __float2bfloat16(y[j]);
        float hf = __bfloat162float(h);
        __hip_bfloat16 l = __float2bfloat16(y[j] - hf);
        ph[j] = *(unsigned short*)&h;
        pl[j] = *(unsigned short*)&l;
    }
    ((ushort4*)Hh)[i] = vh;
    ((ushort4*)Hl)[i] = vl;
}

// ---------------- segmented mean pool with fused layer-2 BN+ReLU ----------------
__global__ __launch_bounds__(128) void pool_seg_kernel(const float* __restrict__ Z,
                                                       const float* __restrict__ scale,
                                                       const float* __restrict__ shift,
                                                       const int* __restrict__ batch,
                                                       float* __restrict__ pooled, int N) {
    int g = blockIdx.x;
    __shared__ int bounds[2];
    if (threadIdx.x < 2) {
        int target = g + threadIdx.x;
        int lo = 0, hi = N;
        while (lo < hi) {
            int mid = (lo + hi) >> 1;
            if (batch[mid] < target) lo = mid + 1;
            else hi = mid;
        }
        bounds[threadIdx.x] = lo;
    }
    __syncthreads();
    int start = bounds[0], end = bounds[1];
    int c = threadIdx.x;
    float sc = scale[c], sh = shift[c];
    float s = 0.f;
    for (int n = start; n < end; n++)
        s += fmaxf(fmaf(Z[(size_t)n * HID + c], sc, sh), 0.f);
    float cntf = (float)(end - start);
    pooled[(size_t)g * HID + c] = s / fmaxf(cntf, 1.f);
}

// ---------------- MLP head ----------------
__global__ __launch_bounds__(64) void head_kernel(const float* __restrict__ pooled,
                                                  const float* __restrict__ Wh1,
                                                  const float* __restrict__ bh1,
                                                  const float* __restrict__ Wh2,
                                                  const float* __restrict__ bh2,
                                                  float* __restrict__ out, int ng) {
    int g = blockIdx.x;
    if (g >= ng) return;
    int t = threadIdx.x;
    __shared__ float p[128];
    p[t] = pooled[g * HID + t];
    p[t + 64] = pooled[g * HID + 64 + t];
    __syncthreads();
    float acc = bh1[t];
    for (int k = 0; k < 128; k++) acc = fmaf(p[k], Wh1[k * 64 + t], acc);
    acc = fmaxf(acc, 0.f);
    float prod = acc * Wh2[t];
    for (int off = 32; off > 0; off >>= 1) prod += __shfl_down(prod, off);
    if (t == 0) out[g] = prod + bh2[0];
}

extern "C" void kernel_launch(void* const* d_in, const int* in_sizes, int n_in,
                              void* d_out, int out_size, void* d_ws, size_t ws_size,
                              hipStream_t stream) {
    const float* x = (const float*)d_in[0];
    const int* ei = (const int*)d_in[1];
    const int* batch = (const int*)d_in[2];
    const float* Wn[3] = {(const float*)d_in[3], (const float*)d_in[8], (const float*)d_in[13]};
    const float* bb[3] = {(const float*)d_in[4], (const float*)d_in[9], (const float*)d_in[14]};
    const float* Wr[3] = {(const float*)d_in[5], (const float*)d_in[10], (const float*)d_in[15]};
    const float* gg[3] = {(const float*)d_in[6], (const float*)d_in[11], (const float*)d_in[16]};
    const float* be[3] = {(const float*)d_in[7], (const float*)d_in[12], (const float*)d_in[17]};
    const float* Wh1 = (const float*)d_in[18];
    const float* bh1 = (const float*)d_in[19];
    const float* Wh2 = (const float*)d_in[20];
    const float* bh2 = (const float*)d_in[21];
    float* out = (float*)d_out;

    const int N = in_sizes[2];       // 50000
    const int NE = in_sizes[1] / 2;  // 800000
    const int NG = out_size;         // 1000
    const int K0 = in_sizes[0] / N;  // 78
    const int K0pad = ((K0 + 31) / 32) * 32;  // 96

    const int* src = ei;
    const int* dst = ei + NE;

    char* w = (char*)d_ws;
    auto alloc = [&](size_t bytes) -> void* {
        void* p = (void*)w;
        w += (bytes + 255) & ~(size_t)255;
        return p;
    };
    float* bufU = (float*)alloc((size_t)N * HID * 4);
    float* bufV = (float*)alloc((size_t)N * HID * 4);  // Z aliases V
    unsigned short* xh = (unsigned short*)alloc((size_t)N * K0pad * 2);
    unsigned short* xl = (unsigned short*)alloc((size_t)N * K0pad * 2);
    unsigned short* Hh = (unsigned short*)alloc((size_t)N * HID * 2);
    unsigned short* Hl = (unsigned short*)alloc((size_t)N * HID * 2);
    unsigned short* BTh[3];
    unsigned short* BTl[3];
    BTh[0] = (unsigned short*)alloc((size_t)256 * K0pad * 2);
    BTl[0] = (unsigned short*)alloc((size_t)256 * K0pad * 2);
    BTh[1] = (unsigned short*)alloc((size_t)256 * HID * 2);
    BTl[1] = (unsigned short*)alloc((size_t)256 * HID * 2);
    BTh[2] = (unsigned short*)alloc((size_t)256 * HID * 2);
    BTl[2] = (unsigned short*)alloc((size_t)256 * HID * 2);
    int* counts = (int*)alloc((size_t)N * 4);
    int* offsets = (int*)alloc((size_t)(N + 1) * 4);
    int* cursor = (int*)alloc((size_t)N * 4);
    int* esrc = (int*)alloc((size_t)NE * 4);
    int* partials = (int*)alloc(1024 * 4);
    double* stats = (double*)alloc(3 * 2 * HID * 8);  // [layer][sum|sumsq][128]
    float* scale = (float*)alloc(HID * 4);
    float* shift = (float*)alloc(HID * 4);
    float* pooled = (float*)alloc((size_t)NG * HID * 4);
    (void)ws_size;
    (void)n_in;

    // ---- CSR by dst + stat zeroing ----
    int nscb = (N + SCB - 1) / SCB;
    zero_int_kernel<<<(N + 255) / 256, 256, 0, stream>>>(counts, N);
    count_kernel<<<(NE + 255) / 256, 256, 0, stream>>>(dst, counts, NE);
    scan_blocks_kernel<<<nscb, SCB, 0, stream>>>(counts, offsets, partials, N);
    scan_partials_kernel<<<1, 1024, 0, stream>>>(partials, nscb);
    scan_add_kernel<<<nscb, SCB, 0, stream>>>(offsets, partials, cursor, N);
    fill_kernel<<<(NE + 255) / 256, 256, 0, stream>>>(src, dst, cursor, esrc, NE);
    zero_stats_all_kernel<<<3, 256, 0, stream>>>(stats);

    // ---- converts ----
    convert_x_kernel<<<((size_t)N * K0pad + 255) / 256, 256, 0, stream>>>(x, xh, xl, N, K0, K0pad);
    convert_w_kernel<<<(256 * K0pad + 255) / 256, 256, 0, stream>>>(Wn[0], Wr[0], BTh[0], BTl[0], K0, K0pad);
    convert_w_kernel<<<(256 * HID + 255) / 256, 256, 0, stream>>>(Wn[1], Wr[1], BTh[1], BTl[1], HID, HID);
    convert_w_kernel<<<(256 * HID + 255) / 256, 256, 0, stream>>>(Wn[2], Wr[2], BTh[2], BTl[2], HID, HID);

    // ---- 3 SAGE+BN(+ReLU) layers ----
    int gblocks = (N + 63) / 64;
    int total4 = N * HID / 4;
    for (int l = 0; l < 3; l++) {
        const unsigned short* Ah = (l == 0) ? xh : Hh;
        const unsigned short* Al = (l == 0) ? xl : Hl;
        int Kpad = (l == 0) ? K0pad : HID;
        double* sums = stats + l * 2 * HID;
        double* sumsq = sums + HID;
        gemm_mfma_kernel<<<gblocks, 256, 0, stream>>>(Ah, Al, BTh[l], BTl[l], bufU, bufV, N, Kpad);
        agg_kernel<<<(N + 7) / 8, 256, 0, stream>>>(bufU, bufV, bb[l], counts, offsets, esrc, bufV, N);
        stats_kernel<<<512, 256, 0, stream>>>(bufV, sums, sumsq, N);
        bn_finalize_kernel<<<1, 128, 0, stream>>>(sums, sumsq, gg[l], be[l], scale, shift, N);
        if (l < 2) {
            bn_relu_bf16_kernel<<<(total4 + 255) / 256, 256, 0, stream>>>(bufV, scale, shift, Hh, Hl, total4);
        }
        // layer 2: BN+ReLU fused into pool below
    }

    // ---- pool (fused BN+ReLU) + MLP head ----
    pool_seg_kernel<<<NG, 128, 0, stream>>>(bufV, scale, shift, batch, pooled, N);
    head_kernel<<<NG, 64, 0, stream>>>(pooled, Wh1, bh1, Wh2, bh2, out, NG);
}